// Round 11
// baseline (629.503 us; speedup 1.0000x reference)
//
#include <hip/hip_runtime.h>
#include <hip/hip_cooperative_groups.h>

namespace cg = cooperative_groups;

// EdgeConv on dense bipartite graph: A=256, U=1024, D=64.
// out[a,u] = edge@W3t - (relu(edge@W1b+c1[a]) + relu(edge@W2b+c2[u]))@W3b + s3[a] + s4[u]
// with c1 = ap_hid@W1t+b1, c2 = ue_hid@W2t+b2, s3 = ap_sum@W3b, s4 = ue_sum@W3b+b3.
//
// R13: R12's cooperative fusion with the failure mode closed. R12's absmax
// equaled max|ref| => the coop launch errored and was ignored; out stayed 0.
// Now: (a) launch result checked, falling back to the proven R6 4-kernel
// path in the same kernel_launch; (b) phases and fallback kernels share
// byte-identical __device__ bodies; (c) __threadfence() on BOTH sides of
// each grid.sync() (reader-side L2 invalidate, G16 cross-XCD rule).

#define A_N 256
#define U_N 1024

typedef short short8 __attribute__((ext_vector_type(8)));
typedef float f32x4 __attribute__((ext_vector_type(4)));

__device__ __forceinline__ unsigned short f2bf(float f) {
  unsigned int u = __float_as_uint(f);
  return (unsigned short)((u + 0x7FFFu + ((u >> 16) & 1u)) >> 16);  // RNE
}

__device__ __forceinline__ f32x4 mfma16(short8 a, short8 b, f32x4 c) {
  return __builtin_amdgcn_mfma_f32_16x16x32_bf16(a, b, c, 0, 0, 0);
}

__device__ __forceinline__ void cvt16(const float4& e0, const float4& e1,
                                      const float4& e2, const float4& e3,
                                      short8& a0, short8& a1) {
  a0[0] = (short)f2bf(e0.x); a0[1] = (short)f2bf(e0.y);
  a0[2] = (short)f2bf(e0.z); a0[3] = (short)f2bf(e0.w);
  a0[4] = (short)f2bf(e1.x); a0[5] = (short)f2bf(e1.y);
  a0[6] = (short)f2bf(e1.z); a0[7] = (short)f2bf(e1.w);
  a1[0] = (short)f2bf(e2.x); a1[1] = (short)f2bf(e2.y);
  a1[2] = (short)f2bf(e2.z); a1[3] = (short)f2bf(e2.w);
  a1[4] = (short)f2bf(e3.x); a1[5] = (short)f2bf(e3.y);
  a1[6] = (short)f2bf(e3.z); a1[7] = (short)f2bf(e3.w);
}

__device__ __forceinline__ void rowmlp_row(const float* __restrict__ in,
                                           const float* __restrict__ W,
                                           const float* __restrict__ bias,
                                           float* __restrict__ out, int r, int lane) {
  float rv = in[r * 64 + lane];
  float acc = bias ? bias[lane] : 0.f;
#pragma unroll
  for (int k = 0; k < 64; k++) acc += __shfl(rv, k, 64) * W[k * 64 + lane];
  out[r * 64 + lane] = acc;
}

// ======================= shared phase bodies (R6 math) ======================

// Prep unit (0..383): Wt sections / c1 rows / c2 rows.
__device__ __forceinline__ void dev_prep_unit(
    int unit, int tid, const float* __restrict__ ap_hid,
    const float* __restrict__ ue_hid, const float* __restrict__ W1,
    const float* __restrict__ b1, const float* __restrict__ W2,
    const float* __restrict__ b2, const float* __restrict__ W3,
    unsigned short* __restrict__ Wt, float* __restrict__ c1,
    float* __restrict__ c2) {
  if (unit < 64) {
    int idx = unit * 256 + tid;  // 16384 total
    int r = idx >> 6, k = idx & 63;
    int sec = r >> 6, d = r & 63;
    float v;
    if (sec == 0)      v = W1[(64 + k) * 64 + d];
    else if (sec == 1) v = W2[(64 + k) * 64 + d];
    else if (sec == 2) v = W3[k * 64 + d];
    else               v = W3[(64 + k) * 64 + d];
    Wt[r * 64 + k] = f2bf(v);
  } else if (unit < 128) {
    rowmlp_row(ap_hid, W1, b1, c1, (unit - 64) * 4 + (tid >> 6), tid & 63);
  } else {
    rowmlp_row(ue_hid, W2, b2, c2, (unit - 128) * 4 + (tid >> 6), tid & 63);
  }
}

// Pass1 unit (0..1023): chunk=unit>>4 (4 a's), panel=unit&15 (64 u's).
__device__ __forceinline__ void dev_pass1_unit(
    int unit, int tid, float* ap_l, const float* __restrict__ edge,
    const short8 (&bw)[8][2], const float* __restrict__ c1,
    const float* __restrict__ c2, float* __restrict__ ap_part,
    float* __restrict__ ue_part) {
  int lane = tid & 63, w = tid >> 6;
  int fr = lane & 15, fq = lane >> 4;
  int chunk = unit >> 4, panel = unit & 15;
  int a0 = chunk * 4, u0 = panel * 64;
  int urow = u0 + w * 16 + fr;
  const float* erow = edge + urow * 64 + fq * 8;  // + a*65536

  ap_l[tid] = 0.f;
  __syncthreads();

  float c2v[4][4];
#pragma unroll
  for (int j = 0; j < 4; j++)
#pragma unroll
    for (int i = 0; i < 4; i++)
      c2v[j][i] = c2[(u0 + w * 16 + fq * 4 + i) * 64 + j * 16 + fr];

  float ureg[4][4];
#pragma unroll
  for (int j = 0; j < 4; j++)
#pragma unroll
    for (int i = 0; i < 4; i++) ureg[j][i] = 0.f;

  // prefetch slice a0
  const float* p0 = erow + a0 * 65536;
  float4 e0 = *(const float4*)(p0);
  float4 e1 = *(const float4*)(p0 + 4);
  float4 e2 = *(const float4*)(p0 + 32);
  float4 e3 = *(const float4*)(p0 + 36);
  float c1v[4];
#pragma unroll
  for (int j = 0; j < 4; j++) c1v[j] = c1[a0 * 64 + j * 16 + fr];

  for (int c = 0; c < 4; c++) {
    int a = a0 + c;
    float4 n0, n1, n2, n3;
    float nc1[4];
    if (c < 3) {
      const float* np = erow + (a + 1) * 65536;
      n0 = *(const float4*)(np);
      n1 = *(const float4*)(np + 4);
      n2 = *(const float4*)(np + 32);
      n3 = *(const float4*)(np + 36);
#pragma unroll
      for (int j = 0; j < 4; j++) nc1[j] = c1[(a + 1) * 64 + j * 16 + fr];
    }
    short8 af0, af1;
    cvt16(e0, e1, e2, e3, af0, af1);

    // P1 -> reduce over the wave's 16 u-rows -> LDS accumulator (cross-wave)
#pragma unroll
    for (int j = 0; j < 4; j++) {
      f32x4 acc = {0.f, 0.f, 0.f, 0.f};
      acc = mfma16(af0, bw[j][0], acc);
      acc = mfma16(af1, bw[j][1], acc);
      float cv = c1v[j];
      float rs = fmaxf(acc[0] + cv, 0.f) + fmaxf(acc[1] + cv, 0.f) +
                 fmaxf(acc[2] + cv, 0.f) + fmaxf(acc[3] + cv, 0.f);
      rs += __shfl_xor(rs, 16, 64);
      rs += __shfl_xor(rs, 32, 64);
      if (lane < 16) atomicAdd(&ap_l[c * 64 + j * 16 + lane], rs);  // LDS atomic
    }
    // P2 -> per-(u,d) register accumulation across the 4 a's
#pragma unroll
    for (int j = 0; j < 4; j++) {
      f32x4 acc = {0.f, 0.f, 0.f, 0.f};
      acc = mfma16(af0, bw[4 + j][0], acc);
      acc = mfma16(af1, bw[4 + j][1], acc);
#pragma unroll
      for (int i = 0; i < 4; i++)
        ureg[j][i] += fmaxf(acc[i] + c2v[j][i], 0.f);
    }
    if (c < 3) {
      e0 = n0; e1 = n1; e2 = n2; e3 = n3;
#pragma unroll
      for (int j = 0; j < 4; j++) c1v[j] = nc1[j];
    }
  }
  // ue partials: plain stores (unique writer for (chunk, u))
#pragma unroll
  for (int j = 0; j < 4; j++)
#pragma unroll
    for (int i = 0; i < 4; i++)
      ue_part[(chunk * 1024 + u0 + w * 16 + fq * 4 + i) * 64 + j * 16 + fr] =
          ureg[j][i];
  __syncthreads();
  // ap partials: one per thread (unique writer for (panel, a))
  ap_part[(panel * 256 + a0 + w) * 64 + lane] = ap_l[tid];
}

// Mid unit (0..319): s3 (units 0-63), s4 (units 64-319).
__device__ __forceinline__ void dev_mid_unit(
    int unit, int tid, const float* __restrict__ ap_part,
    const float* __restrict__ ue_part, const float* __restrict__ W3,
    const float* __restrict__ b3, float* __restrict__ s3,
    float* __restrict__ s4) {
  int lane = tid & 63, w = tid >> 6;
  const float* W3b = W3 + 4096;
  if (unit < 64) {
    int r = unit * 4 + w;
    float v = 0.f;
#pragma unroll
    for (int p = 0; p < 16; p++) v += ap_part[(p * 256 + r) * 64 + lane];
    float acc = 0.f;
#pragma unroll
    for (int k = 0; k < 64; k++) acc += __shfl(v, k, 64) * W3b[k * 64 + lane];
    s3[r * 64 + lane] = acc;
  } else {
    int r = (unit - 64) * 4 + w;
    float v = 0.f;
#pragma unroll
    for (int p = 0; p < 64; p++) v += ue_part[(p * 1024 + r) * 64 + lane];
    float acc = b3[lane];
#pragma unroll
    for (int k = 0; k < 64; k++) acc += __shfl(v, k, 64) * W3b[k * 64 + lane];
    s4[r * 64 + lane] = acc;
  }
}

__device__ __forceinline__ void stage_Wlds(unsigned short* W_lds,
                                           const unsigned short* __restrict__ Wt,
                                           int tid) {
#pragma unroll
  for (int it = 0; it < 8; it++) {
    int r = it * 32 + (tid >> 3), seg = tid & 7;
    *(uint4*)&W_lds[r * 72 + seg * 8] = *(const uint4*)(Wt + r * 64 + seg * 8);
  }
}

// Pass2 unit (0..1023): a=unit>>2, 4 u-panels, R6 pipeline.
__device__ __forceinline__ void dev_pass2_unit(
    int unit, int tid, const unsigned short* W_lds, unsigned short* t_lds,
    const float* __restrict__ edge, const float* __restrict__ c1,
    const float* __restrict__ c2, const float* __restrict__ s3,
    const float* __restrict__ s4, float* __restrict__ out) {
  int lane = tid & 63, w = tid >> 6;
  int fr = lane & 15, fq = lane >> 4;
  int a = unit >> 2;
  int ubase = (unit & 3) * 256;

  float c1v[4], s3v[4];
#pragma unroll
  for (int j = 0; j < 4; j++) {
    c1v[j] = c1[a * 64 + j * 16 + fr];
    s3v[j] = s3[a * 64 + j * 16 + fr];
  }

  // prefetch panel 0: edge tile + c2/s4 scalars
  const float* er0 = edge + (a * 1024 + ubase + w * 16 + fr) * 64 + fq * 8;
  float4 e0 = *(const float4*)(er0);
  float4 e1 = *(const float4*)(er0 + 4);
  float4 e2 = *(const float4*)(er0 + 32);
  float4 e3 = *(const float4*)(er0 + 36);
  float c2v[4][4], s4v[4][4];
#pragma unroll
  for (int j = 0; j < 4; j++)
#pragma unroll
    for (int i = 0; i < 4; i++) {
      int u = ubase + w * 16 + fq * 4 + i;
      c2v[j][i] = c2[u * 64 + j * 16 + fr];
      s4v[j][i] = s4[u * 64 + j * 16 + fr];
    }

  for (int pnl = 0; pnl < 4; pnl++) {
    int upan = ubase + pnl * 64;
    float4 n0, n1, n2, n3;
    float c2n[4][4], s4n[4][4];
    if (pnl < 3) {
      const float* nr = edge + (a * 1024 + upan + 64 + w * 16 + fr) * 64 + fq * 8;
      n0 = *(const float4*)(nr);
      n1 = *(const float4*)(nr + 4);
      n2 = *(const float4*)(nr + 32);
      n3 = *(const float4*)(nr + 36);
#pragma unroll
      for (int j = 0; j < 4; j++)
#pragma unroll
        for (int i = 0; i < 4; i++) {
          int u = upan + 64 + w * 16 + fq * 4 + i;
          c2n[j][i] = c2[u * 64 + j * 16 + fr];
          s4n[j][i] = s4[u * 64 + j * 16 + fr];
        }
    }
    short8 af0, af1;
    cvt16(e0, e1, e2, e3, af0, af1);

    f32x4 accP3[4];
#pragma unroll
    for (int j = 0; j < 4; j++) {
      const unsigned short* wr = &W_lds[(j * 16 + fr) * 72 + fq * 8];
      short8 b10 = *(const short8*)(wr);
      short8 b11 = *(const short8*)(wr + 32);
      short8 b20 = *(const short8*)(wr + 64 * 72);
      short8 b21 = *(const short8*)(wr + 64 * 72 + 32);
      short8 b30 = *(const short8*)(wr + 128 * 72);
      short8 b31 = *(const short8*)(wr + 128 * 72 + 32);
      f32x4 a1 = {0.f, 0.f, 0.f, 0.f};
      a1 = mfma16(af0, b10, a1);
      a1 = mfma16(af1, b11, a1);
      f32x4 a2 = {0.f, 0.f, 0.f, 0.f};
      a2 = mfma16(af0, b20, a2);
      a2 = mfma16(af1, b21, a2);
      f32x4 p3 = {0.f, 0.f, 0.f, 0.f};
      p3 = mfma16(af0, b30, p3);
      p3 = mfma16(af1, b31, p3);
      accP3[j] = p3;
#pragma unroll
      for (int i = 0; i < 4; i++) {
        float tv = fmaxf(a1[i] + c1v[j], 0.f) + fmaxf(a2[i] + c2v[j][i], 0.f);
        t_lds[(w * 16 + fq * 4 + i) * 72 + j * 16 + fr] = f2bf(tv);  // wave-private
      }
    }
    // GEMM2: A = t (wave's own rows; DS in-order per wave, no barrier)
    short8 tf0 = *(const short8*)&t_lds[(w * 16 + fr) * 72 + fq * 8];
    short8 tf1 = *(const short8*)&t_lds[(w * 16 + fr) * 72 + 32 + fq * 8];
#pragma unroll
    for (int j = 0; j < 4; j++) {
      const unsigned short* wr = &W_lds[(192 + j * 16 + fr) * 72 + fq * 8];
      short8 b0 = *(const short8*)(wr);
      short8 b1 = *(const short8*)(wr + 32);
      f32x4 acc = {0.f, 0.f, 0.f, 0.f};
      acc = mfma16(tf0, b0, acc);
      acc = mfma16(tf1, b1, acc);
#pragma unroll
      for (int i = 0; i < 4; i++) {
        int u = upan + w * 16 + fq * 4 + i;
        out[(a * 1024 + u) * 64 + j * 16 + fr] =
            accP3[j][i] - acc[i] + s3v[j] + s4v[j][i];
      }
    }
    if (pnl < 3) {
      e0 = n0; e1 = n1; e2 = n2; e3 = n3;
#pragma unroll
      for (int j = 0; j < 4; j++)
#pragma unroll
        for (int i = 0; i < 4; i++) {
          c2v[j][i] = c2n[j][i];
          s4v[j][i] = s4n[j][i];
        }
    }
  }
}

// ======================= standalone (fallback) kernels ======================

__global__ __launch_bounds__(256) void k_prep(
    const float* __restrict__ ap_hid, const float* __restrict__ ue_hid,
    const float* __restrict__ W1, const float* __restrict__ b1,
    const float* __restrict__ W2, const float* __restrict__ b2,
    const float* __restrict__ W3, unsigned short* __restrict__ Wt,
    float* __restrict__ c1, float* __restrict__ c2) {
  dev_prep_unit(blockIdx.x, threadIdx.x, ap_hid, ue_hid, W1, b1, W2, b2, W3,
                Wt, c1, c2);
}

__global__ __launch_bounds__(256) void k_pass1(
    const float* __restrict__ edge, const unsigned short* __restrict__ Wt,
    const float* __restrict__ c1, const float* __restrict__ c2,
    float* __restrict__ ap_part, float* __restrict__ ue_part) {
  __shared__ float ap_l[256];
  int tid = threadIdx.x, lane = tid & 63;
  int fr = lane & 15, fq = lane >> 4;
  short8 bw[8][2];
#pragma unroll
  for (int nt = 0; nt < 8; nt++)
#pragma unroll
    for (int ks = 0; ks < 2; ks++)
      bw[nt][ks] = *(const short8*)(Wt + (nt * 16 + fr) * 64 + ks * 32 + fq * 8);
  dev_pass1_unit(blockIdx.x, tid, ap_l, edge, bw, c1, c2, ap_part, ue_part);
}

__global__ __launch_bounds__(256) void k_mid(
    const float* __restrict__ ap_part, const float* __restrict__ ue_part,
    const float* __restrict__ W3, const float* __restrict__ b3,
    float* __restrict__ s3, float* __restrict__ s4) {
  dev_mid_unit(blockIdx.x, threadIdx.x, ap_part, ue_part, W3, b3, s3, s4);
}

__global__ __launch_bounds__(256) void k_pass2(
    const float* __restrict__ edge, const unsigned short* __restrict__ Wt,
    const float* __restrict__ c1, const float* __restrict__ c2,
    const float* __restrict__ s3, const float* __restrict__ s4,
    float* __restrict__ out) {
  __shared__ unsigned short W_lds[256 * 72];
  __shared__ unsigned short t_lds[64 * 72];
  stage_Wlds(W_lds, Wt, threadIdx.x);
  __syncthreads();
  dev_pass2_unit(blockIdx.x, threadIdx.x, W_lds, t_lds, edge, c1, c2, s3, s4,
                 out);
}

// ============================ cooperative kernel ============================

__global__ __launch_bounds__(256, 2) void k_fused(
    const float* __restrict__ edge, const float* __restrict__ ap_hid,
    const float* __restrict__ ue_hid,
    const float* __restrict__ W1, const float* __restrict__ b1,
    const float* __restrict__ W2, const float* __restrict__ b2,
    const float* __restrict__ W3, const float* __restrict__ b3,
    unsigned short* __restrict__ Wt, float* __restrict__ c1,
    float* __restrict__ c2, float* __restrict__ s3, float* __restrict__ s4,
    float* __restrict__ ap_part, float* __restrict__ ue_part,
    float* __restrict__ out) {
  __shared__ unsigned short W_lds[256 * 72];  // 36.9KB (pass2)
  __shared__ unsigned short t_lds[64 * 72];   // 9.2KB  (pass2)
  __shared__ float ap_l[256];                 // 1KB    (pass1)
  cg::grid_group grid = cg::this_grid();
  int bx = blockIdx.x, tid = threadIdx.x, lane = tid & 63;
  int fr = lane & 15, fq = lane >> 4;

  // P0: prep (384 units on 512 blocks)
  if (bx < 384)
    dev_prep_unit(bx, tid, ap_hid, ue_hid, W1, b1, W2, b2, W3, Wt, c1, c2);
  __threadfence();
  grid.sync();
  __threadfence();  // reader-side invalidate (G16)

  // P1: pass1 (1024 units, 2 per block)
  {
    short8 bw[8][2];
#pragma unroll
    for (int nt = 0; nt < 8; nt++)
#pragma unroll
      for (int ks = 0; ks < 2; ks++)
        bw[nt][ks] = *(const short8*)(Wt + (nt * 16 + fr) * 64 + ks * 32 + fq * 8);
    dev_pass1_unit(bx, tid, ap_l, edge, bw, c1, c2, ap_part, ue_part);
    __syncthreads();
    dev_pass1_unit(bx + 512, tid, ap_l, edge, bw, c1, c2, ap_part, ue_part);
  }
  __threadfence();
  grid.sync();
  __threadfence();

  // P2: mid (320 units)
  if (bx < 320) dev_mid_unit(bx, tid, ap_part, ue_part, W3, b3, s3, s4);
  __threadfence();
  grid.sync();
  __threadfence();

  // P3: pass2 (1024 units, 2 per block; W_lds staged once)
  stage_Wlds(W_lds, Wt, tid);
  __syncthreads();
  dev_pass2_unit(bx, tid, W_lds, t_lds, edge, c1, c2, s3, s4, out);
  dev_pass2_unit(bx + 512, tid, W_lds, t_lds, edge, c1, c2, s3, s4, out);
}

extern "C" void kernel_launch(void* const* d_in, const int* in_sizes, int n_in,
                              void* d_out, int out_size, void* d_ws, size_t ws_size,
                              hipStream_t stream) {
  const float* ap_hid = (const float*)d_in[0];
  const float* ue_hid = (const float*)d_in[1];
  const float* edge   = (const float*)d_in[2];
  const float* W1     = (const float*)d_in[3];
  const float* b1     = (const float*)d_in[4];
  const float* W2     = (const float*)d_in[5];
  const float* b2     = (const float*)d_in[6];
  const float* W3     = (const float*)d_in[7];
  const float* b3     = (const float*)d_in[8];
  float* out = (float*)d_out;

  char* ws = (char*)d_ws;
  unsigned short* Wt = (unsigned short*)ws;            //     32768 B
  float* c1      = (float*)(ws + 32768);               //     65536 B
  float* c2      = (float*)(ws + 98304);               //    262144 B
  float* s3      = (float*)(ws + 360448);              //     65536 B
  float* s4      = (float*)(ws + 425984);              //    262144 B
  float* ap_part = (float*)(ws + 688128);              //   4194304 B  [16][256][64]
  float* ue_part = (float*)(ws + 4882432);             //  16777216 B  [64][1024][64]

  void* args[] = {(void*)&edge, (void*)&ap_hid, (void*)&ue_hid,
                  (void*)&W1, (void*)&b1, (void*)&W2, (void*)&b2,
                  (void*)&W3, (void*)&b3, (void*)&Wt, (void*)&c1, (void*)&c2,
                  (void*)&s3, (void*)&s4, (void*)&ap_part, (void*)&ue_part,
                  (void*)&out};
  hipError_t err = hipLaunchCooperativeKernel((const void*)k_fused, dim3(512),
                                              dim3(256), args, 0, stream);
  if (err != hipSuccess) {
    (void)hipGetLastError();  // clear sticky error; fall back to 4-kernel path
    k_prep<<<384, 256, 0, stream>>>(ap_hid, ue_hid, W1, b1, W2, b2, W3, Wt,
                                    c1, c2);
    k_pass1<<<1024, 256, 0, stream>>>(edge, Wt, c1, c2, ap_part, ue_part);
    k_mid<<<320, 256, 0, stream>>>(ap_part, ue_part, W3, b3, s3, s4);
    k_pass2<<<1024, 256, 0, stream>>>(edge, Wt, c1, c2, s3, s4, out);
  }
}

// Round 12
// 161.059 us; speedup vs baseline: 3.9085x; 3.9085x over previous
//
#include <hip/hip_runtime.h>

// EdgeConv on dense bipartite graph: A=256, U=1024, D=64.
// out[a,u] = edge@W3t - (relu(edge@W1b+c1[a]) + relu(edge@W2b+c2[u]))@W3b + s3[a] + s4[u]
// with c1 = ap_hid@W1t+b1, c2 = ue_hid@W2t+b2, s3 = ap_sum@W3b, s4 = ue_sum@W3b+b3.
//
// R14: R6 structure (best measured: 168.7us; R11 proved coop fusion is 3x
// worse) with ONE change in the only untested direction: k_pass1 goes 4-a ->
// 8-a chunks (512 blocks). Mechanism: both prior orderings showed deeper
// per-block pipelines + less partials traffic win (R4's 2-a regressed, R5's
// 1-panel pass2 regressed). 8-a: 2x setup amortization, ue_part 16->8MB,
// k_mid ue reduction 64->32 partials. All else byte-identical to R6.

#define A_N 256
#define U_N 1024

typedef short short8 __attribute__((ext_vector_type(8)));
typedef float f32x4 __attribute__((ext_vector_type(4)));

__device__ __forceinline__ unsigned short f2bf(float f) {
  unsigned int u = __float_as_uint(f);
  return (unsigned short)((u + 0x7FFFu + ((u >> 16) & 1u)) >> 16);  // RNE
}

__device__ __forceinline__ f32x4 mfma16(short8 a, short8 b, f32x4 c) {
  return __builtin_amdgcn_mfma_f32_16x16x32_bf16(a, b, c, 0, 0, 0);
}

__device__ __forceinline__ void cvt16(const float4& e0, const float4& e1,
                                      const float4& e2, const float4& e3,
                                      short8& a0, short8& a1) {
  a0[0] = (short)f2bf(e0.x); a0[1] = (short)f2bf(e0.y);
  a0[2] = (short)f2bf(e0.z); a0[3] = (short)f2bf(e0.w);
  a0[4] = (short)f2bf(e1.x); a0[5] = (short)f2bf(e1.y);
  a0[6] = (short)f2bf(e1.z); a0[7] = (short)f2bf(e1.w);
  a1[0] = (short)f2bf(e2.x); a1[1] = (short)f2bf(e2.y);
  a1[2] = (short)f2bf(e2.z); a1[3] = (short)f2bf(e2.w);
  a1[4] = (short)f2bf(e3.x); a1[5] = (short)f2bf(e3.y);
  a1[6] = (short)f2bf(e3.z); a1[7] = (short)f2bf(e3.w);
}

__device__ __forceinline__ void rowmlp_row(const float* __restrict__ in,
                                           const float* __restrict__ W,
                                           const float* __restrict__ bias,
                                           float* __restrict__ out, int r, int lane) {
  float rv = in[r * 64 + lane];
  float acc = bias ? bias[lane] : 0.f;
#pragma unroll
  for (int k = 0; k < 64; k++) acc += __shfl(rv, k, 64) * W[k * 64 + lane];
  out[r * 64 + lane] = acc;
}

// Fused setup: build Wt (bf16, n-major, 4 sections), c1, c2.
// Wt rows 0-63: W1_bot^T, 64-127: W2_bot^T, 128-191: W3_top^T, 192-255: W3_bot^T
__global__ __launch_bounds__(256) void k_prep(
    const float* __restrict__ ap_hid, const float* __restrict__ ue_hid,
    const float* __restrict__ W1, const float* __restrict__ b1,
    const float* __restrict__ W2, const float* __restrict__ b2,
    const float* __restrict__ W3, unsigned short* __restrict__ Wt,
    float* __restrict__ c1, float* __restrict__ c2) {
  int bx = blockIdx.x, tid = threadIdx.x;
  if (bx < 64) {
    int idx = bx * 256 + tid;  // 16384 total
    int r = idx >> 6, k = idx & 63;
    int sec = r >> 6, d = r & 63;
    float v;
    if (sec == 0)      v = W1[(64 + k) * 64 + d];
    else if (sec == 1) v = W2[(64 + k) * 64 + d];
    else if (sec == 2) v = W3[k * 64 + d];
    else               v = W3[(64 + k) * 64 + d];
    Wt[r * 64 + k] = f2bf(v);
  } else if (bx < 128) {
    int r = (bx - 64) * 4 + (tid >> 6);
    rowmlp_row(ap_hid, W1, b1, c1, r, tid & 63);
  } else {  // bx in [128, 384)
    int r = (bx - 128) * 4 + (tid >> 6);
    rowmlp_row(ue_hid, W2, b2, c2, r, tid & 63);
  }
}

// Pass 1 (atomic-free): per-block PARTIAL sums, 8-a chunks (deep pipeline:
// next-slice edge+c1 prefetched into registers during compute; per-block
// setup amortized over 8 slices; ue_part traffic halved vs 4-a).
//   ue_part[chunk][u][d] : register-accumulated over the block's 8 a's.
//   ap_part[panel][a][d] : cross-wave reduce via LDS accumulator.
// 512 blocks: chunk = bx>>4 (32 chunks of 8 a's), panel = bx&15 (16 u-panels).
__global__ __launch_bounds__(256) void k_pass1(
    const float* __restrict__ edge, const unsigned short* __restrict__ Wt,
    const float* __restrict__ c1, const float* __restrict__ c2,
    float* __restrict__ ap_part, float* __restrict__ ue_part) {
  __shared__ float ap_l[8 * 64];  // [slice c][d]
  int tid = threadIdx.x, lane = tid & 63, w = tid >> 6;
  int fr = lane & 15, fq = lane >> 4;
  int chunk = blockIdx.x >> 4;
  int panel = blockIdx.x & 15;
  int a0 = chunk * 8;
  int u0 = panel * 64;
  int urow = u0 + w * 16 + fr;
  const float* erow = edge + urow * 64 + fq * 8;  // + a*65536

  ap_l[tid] = 0.f;
  ap_l[tid + 256] = 0.f;
  __syncthreads();

  // loop-invariant B-fragments: n-tiles 0-3 = W1b, 4-7 = W2b (held in regs)
  short8 bw[8][2];
#pragma unroll
  for (int nt = 0; nt < 8; nt++)
#pragma unroll
    for (int ks = 0; ks < 2; ks++)
      bw[nt][ks] = *(const short8*)(Wt + (nt * 16 + fr) * 64 + ks * 32 + fq * 8);

  float c2v[4][4];
#pragma unroll
  for (int j = 0; j < 4; j++)
#pragma unroll
    for (int i = 0; i < 4; i++)
      c2v[j][i] = c2[(u0 + w * 16 + fq * 4 + i) * 64 + j * 16 + fr];

  float ureg[4][4];
#pragma unroll
  for (int j = 0; j < 4; j++)
#pragma unroll
    for (int i = 0; i < 4; i++) ureg[j][i] = 0.f;

  // prefetch slice a0
  const float* p0 = erow + a0 * 65536;
  float4 e0 = *(const float4*)(p0);
  float4 e1 = *(const float4*)(p0 + 4);
  float4 e2 = *(const float4*)(p0 + 32);
  float4 e3 = *(const float4*)(p0 + 36);
  float c1v[4];
#pragma unroll
  for (int j = 0; j < 4; j++) c1v[j] = c1[a0 * 64 + j * 16 + fr];

  for (int c = 0; c < 8; c++) {
    int a = a0 + c;
    float4 n0, n1, n2, n3;
    float nc1[4];
    if (c < 7) {
      const float* np = erow + (a + 1) * 65536;
      n0 = *(const float4*)(np);
      n1 = *(const float4*)(np + 4);
      n2 = *(const float4*)(np + 32);
      n3 = *(const float4*)(np + 36);
#pragma unroll
      for (int j = 0; j < 4; j++) nc1[j] = c1[(a + 1) * 64 + j * 16 + fr];
    }
    short8 af0, af1;
    cvt16(e0, e1, e2, e3, af0, af1);

    // P1 -> reduce over the wave's 16 u-rows -> LDS accumulator (cross-wave)
#pragma unroll
    for (int j = 0; j < 4; j++) {
      f32x4 acc = {0.f, 0.f, 0.f, 0.f};
      acc = mfma16(af0, bw[j][0], acc);
      acc = mfma16(af1, bw[j][1], acc);
      float cv = c1v[j];
      float rs = fmaxf(acc[0] + cv, 0.f) + fmaxf(acc[1] + cv, 0.f) +
                 fmaxf(acc[2] + cv, 0.f) + fmaxf(acc[3] + cv, 0.f);
      rs += __shfl_xor(rs, 16, 64);
      rs += __shfl_xor(rs, 32, 64);
      if (lane < 16) atomicAdd(&ap_l[c * 64 + j * 16 + lane], rs);  // LDS atomic
    }
    // P2 -> per-(u,d) register accumulation across the 8 a's
#pragma unroll
    for (int j = 0; j < 4; j++) {
      f32x4 acc = {0.f, 0.f, 0.f, 0.f};
      acc = mfma16(af0, bw[4 + j][0], acc);
      acc = mfma16(af1, bw[4 + j][1], acc);
#pragma unroll
      for (int i = 0; i < 4; i++)
        ureg[j][i] += fmaxf(acc[i] + c2v[j][i], 0.f);
    }
    if (c < 7) {
      e0 = n0; e1 = n1; e2 = n2; e3 = n3;
#pragma unroll
      for (int j = 0; j < 4; j++) c1v[j] = nc1[j];
    }
  }
  // ue partials: plain stores (this block is the unique writer for (chunk, u))
#pragma unroll
  for (int j = 0; j < 4; j++)
#pragma unroll
    for (int i = 0; i < 4; i++)
      ue_part[(chunk * 1024 + u0 + w * 16 + fq * 4 + i) * 64 + j * 16 + fr] =
          ureg[j][i];
  __syncthreads();
  // ap partials: two per thread (this block is the unique writer for (panel, a))
  ap_part[(panel * 256 + a0 + w) * 64 + lane] = ap_l[w * 64 + lane];
  ap_part[(panel * 256 + a0 + 4 + w) * 64 + lane] = ap_l[(4 + w) * 64 + lane];
}

// Mid (R6 form): reduce partials -> row sums -> fused row-MLP:
// s3 = ap_sum@W3b, s4 = ue_sum@W3b + b3.  320 blocks x 4 rows.
__global__ __launch_bounds__(256) void k_mid(
    const float* __restrict__ ap_part, const float* __restrict__ ue_part,
    const float* __restrict__ W3, const float* __restrict__ b3,
    float* __restrict__ s3, float* __restrict__ s4) {
  int bx = blockIdx.x, tid = threadIdx.x, lane = tid & 63;
  const float* W3b = W3 + 4096;
  if (bx < 64) {
    int r = bx * 4 + (tid >> 6);
    float v = 0.f;
#pragma unroll
    for (int p = 0; p < 16; p++) v += ap_part[(p * 256 + r) * 64 + lane];
    float acc = 0.f;
#pragma unroll
    for (int k = 0; k < 64; k++) acc += __shfl(v, k, 64) * W3b[k * 64 + lane];
    s3[r * 64 + lane] = acc;
  } else {  // bx in [64, 320)
    int r = (bx - 64) * 4 + (tid >> 6);
    float v = 0.f;
#pragma unroll
    for (int p = 0; p < 32; p++) v += ue_part[(p * 1024 + r) * 64 + lane];
    float acc = b3[lane];
#pragma unroll
    for (int k = 0; k < 64; k++) acc += __shfl(v, k, 64) * W3b[k * 64 + lane];
    s4[r * 64 + lane] = acc;
  }
}

// Pass 2 (R6 form, unchanged): out = P3 - t@W3b + s3[a] + s4[u],
// t = relu(P1+c1)+relu(P2+c2). 1024 blocks: one a x 4 u-panels, pipelined.
// Edge A-frags AND c2/s4 scalars for panel p+1 prefetched into registers
// during panel p compute. Weights in padded LDS (one barrier); t round-trips
// through wave-private LDS rows (no barrier).
__global__ __launch_bounds__(256) void k_pass2(
    const float* __restrict__ edge, const unsigned short* __restrict__ Wt,
    const float* __restrict__ c1, const float* __restrict__ c2,
    const float* __restrict__ s3, const float* __restrict__ s4,
    float* __restrict__ out) {
  __shared__ unsigned short W_lds[256 * 72];  // 4 sections x 64 rows, pad->72
  __shared__ unsigned short t_lds[64 * 72];
  int tid = threadIdx.x, lane = tid & 63, w = tid >> 6;
  int fr = lane & 15, fq = lane >> 4;
  int a = blockIdx.x >> 2;
  int ubase = (blockIdx.x & 3) * 256;

  // stage all weights into LDS (256 rows x 128B)
#pragma unroll
  for (int it = 0; it < 8; it++) {
    int r = it * 32 + (tid >> 3), seg = tid & 7;
    *(uint4*)&W_lds[r * 72 + seg * 8] = *(const uint4*)(Wt + r * 64 + seg * 8);
  }

  float c1v[4], s3v[4];
#pragma unroll
  for (int j = 0; j < 4; j++) {
    c1v[j] = c1[a * 64 + j * 16 + fr];
    s3v[j] = s3[a * 64 + j * 16 + fr];
  }

  // prefetch panel 0: edge tile + c2/s4 scalars (hide under staging barrier)
  const float* er0 = edge + (a * 1024 + ubase + w * 16 + fr) * 64 + fq * 8;
  float4 e0 = *(const float4*)(er0);
  float4 e1 = *(const float4*)(er0 + 4);
  float4 e2 = *(const float4*)(er0 + 32);
  float4 e3 = *(const float4*)(er0 + 36);
  float c2v[4][4], s4v[4][4];
#pragma unroll
  for (int j = 0; j < 4; j++)
#pragma unroll
    for (int i = 0; i < 4; i++) {
      int u = ubase + w * 16 + fq * 4 + i;
      c2v[j][i] = c2[u * 64 + j * 16 + fr];
      s4v[j][i] = s4[u * 64 + j * 16 + fr];
    }

  __syncthreads();

  for (int pnl = 0; pnl < 4; pnl++) {
    int upan = ubase + pnl * 64;
    float4 n0, n1, n2, n3;
    float c2n[4][4], s4n[4][4];
    if (pnl < 3) {
      const float* nr = edge + (a * 1024 + upan + 64 + w * 16 + fr) * 64 + fq * 8;
      n0 = *(const float4*)(nr);
      n1 = *(const float4*)(nr + 4);
      n2 = *(const float4*)(nr + 32);
      n3 = *(const float4*)(nr + 36);
#pragma unroll
      for (int j = 0; j < 4; j++)
#pragma unroll
        for (int i = 0; i < 4; i++) {
          int u = upan + 64 + w * 16 + fq * 4 + i;
          c2n[j][i] = c2[u * 64 + j * 16 + fr];
          s4n[j][i] = s4[u * 64 + j * 16 + fr];
        }
    }
    short8 af0, af1;
    cvt16(e0, e1, e2, e3, af0, af1);

    f32x4 accP3[4];
#pragma unroll
    for (int j = 0; j < 4; j++) {
      const unsigned short* wr = &W_lds[(j * 16 + fr) * 72 + fq * 8];
      short8 b10 = *(const short8*)(wr);
      short8 b11 = *(const short8*)(wr + 32);
      short8 b20 = *(const short8*)(wr + 64 * 72);
      short8 b21 = *(const short8*)(wr + 64 * 72 + 32);
      short8 b30 = *(const short8*)(wr + 128 * 72);
      short8 b31 = *(const short8*)(wr + 128 * 72 + 32);
      f32x4 a1 = {0.f, 0.f, 0.f, 0.f};
      a1 = mfma16(af0, b10, a1);
      a1 = mfma16(af1, b11, a1);
      f32x4 a2 = {0.f, 0.f, 0.f, 0.f};
      a2 = mfma16(af0, b20, a2);
      a2 = mfma16(af1, b21, a2);
      f32x4 p3 = {0.f, 0.f, 0.f, 0.f};
      p3 = mfma16(af0, b30, p3);
      p3 = mfma16(af1, b31, p3);
      accP3[j] = p3;
#pragma unroll
      for (int i = 0; i < 4; i++) {
        float tv = fmaxf(a1[i] + c1v[j], 0.f) + fmaxf(a2[i] + c2v[j][i], 0.f);
        t_lds[(w * 16 + fq * 4 + i) * 72 + j * 16 + fr] = f2bf(tv);  // wave-private
      }
    }
    // GEMM2: A = t (this wave's own rows; DS in-order per wave, no barrier)
    short8 tf0 = *(const short8*)&t_lds[(w * 16 + fr) * 72 + fq * 8];
    short8 tf1 = *(const short8*)&t_lds[(w * 16 + fr) * 72 + 32 + fq * 8];
#pragma unroll
    for (int j = 0; j < 4; j++) {
      const unsigned short* wr = &W_lds[(192 + j * 16 + fr) * 72 + fq * 8];
      short8 b0 = *(const short8*)(wr);
      short8 b1 = *(const short8*)(wr + 32);
      f32x4 acc = {0.f, 0.f, 0.f, 0.f};
      acc = mfma16(tf0, b0, acc);
      acc = mfma16(tf1, b1, acc);
#pragma unroll
      for (int i = 0; i < 4; i++) {
        int u = upan + w * 16 + fq * 4 + i;
        out[(a * 1024 + u) * 64 + j * 16 + fr] =
            accP3[j][i] - acc[i] + s3v[j] + s4v[j][i];
      }
    }
    if (pnl < 3) {
      e0 = n0; e1 = n1; e2 = n2; e3 = n3;
#pragma unroll
      for (int j = 0; j < 4; j++)
#pragma unroll
        for (int i = 0; i < 4; i++) {
          c2v[j][i] = c2n[j][i];
          s4v[j][i] = s4n[j][i];
        }
    }
  }
}

extern "C" void kernel_launch(void* const* d_in, const int* in_sizes, int n_in,
                              void* d_out, int out_size, void* d_ws, size_t ws_size,
                              hipStream_t stream) {
  const float* ap_hid = (const float*)d_in[0];
  const float* ue_hid = (const float*)d_in[1];
  const float* edge   = (const float*)d_in[2];
  const float* W1     = (const float*)d_in[3];
  const float* b1     = (const float*)d_in[4];
  const float* W2     = (const float*)d_in[5];
  const float* b2     = (const float*)d_in[6];
  const float* W3     = (const float*)d_in[7];
  const float* b3     = (const float*)d_in[8];
  float* out = (float*)d_out;

  char* ws = (char*)d_ws;
  unsigned short* Wt = (unsigned short*)ws;            //     32768 B
  float* c1      = (float*)(ws + 32768);               //     65536 B
  float* c2      = (float*)(ws + 98304);               //    262144 B
  float* s3      = (float*)(ws + 360448);              //     65536 B
  float* s4      = (float*)(ws + 425984);              //    262144 B
  float* ap_part = (float*)(ws + 688128);              //   4194304 B  [16][256][64]
  float* ue_part = (float*)(ws + 4882432);             //   8388608 B  [32][1024][64]

  k_prep<<<384, 256, 0, stream>>>(ap_hid, ue_hid, W1, b1, W2, b2, W3, Wt, c1, c2);
  k_pass1<<<512, 256, 0, stream>>>(edge, Wt, c1, c2, ap_part, ue_part);
  k_mid<<<320, 256, 0, stream>>>(ap_part, ue_part, W3, b3, s3, s4);
  k_pass2<<<1024, 256, 0, stream>>>(edge, Wt, c1, c2, s3, s4, out);
}

// Round 13
// 157.317 us; speedup vs baseline: 4.0015x; 1.0238x over previous
//
#include <hip/hip_runtime.h>

// EdgeConv on dense bipartite graph: A=256, U=1024, D=64.
// out[a,u] = edge@W3t - (relu(edge@W1b+c1[a]) + relu(edge@W2b+c2[u]))@W3b + s3[a] + s4[u]
// with c1 = ap_hid@W1t+b1, c2 = ue_hid@W2t+b2, s3 = ap_sum@W3b, s4 = ue_sum@W3b+b3.
//
// R15: R14 (best measured: 161.1us) with the SAME winning move applied to
// k_pass2: 1024 -> 256 blocks, one a per block, 16-panel pipeline (was 4).
// W_lds staging + c1/s3 + cold-start/drain amortize 4x; per-panel body
// byte-identical. (R14 proved the "fewer, deeper blocks" gradient on pass1:
// 8-a chunks won ~8us; R4/R5 showed the opposite direction loses.)

#define A_N 256
#define U_N 1024

typedef short short8 __attribute__((ext_vector_type(8)));
typedef float f32x4 __attribute__((ext_vector_type(4)));

__device__ __forceinline__ unsigned short f2bf(float f) {
  unsigned int u = __float_as_uint(f);
  return (unsigned short)((u + 0x7FFFu + ((u >> 16) & 1u)) >> 16);  // RNE
}

__device__ __forceinline__ f32x4 mfma16(short8 a, short8 b, f32x4 c) {
  return __builtin_amdgcn_mfma_f32_16x16x32_bf16(a, b, c, 0, 0, 0);
}

__device__ __forceinline__ void cvt16(const float4& e0, const float4& e1,
                                      const float4& e2, const float4& e3,
                                      short8& a0, short8& a1) {
  a0[0] = (short)f2bf(e0.x); a0[1] = (short)f2bf(e0.y);
  a0[2] = (short)f2bf(e0.z); a0[3] = (short)f2bf(e0.w);
  a0[4] = (short)f2bf(e1.x); a0[5] = (short)f2bf(e1.y);
  a0[6] = (short)f2bf(e1.z); a0[7] = (short)f2bf(e1.w);
  a1[0] = (short)f2bf(e2.x); a1[1] = (short)f2bf(e2.y);
  a1[2] = (short)f2bf(e2.z); a1[3] = (short)f2bf(e2.w);
  a1[4] = (short)f2bf(e3.x); a1[5] = (short)f2bf(e3.y);
  a1[6] = (short)f2bf(e3.z); a1[7] = (short)f2bf(e3.w);
}

__device__ __forceinline__ void rowmlp_row(const float* __restrict__ in,
                                           const float* __restrict__ W,
                                           const float* __restrict__ bias,
                                           float* __restrict__ out, int r, int lane) {
  float rv = in[r * 64 + lane];
  float acc = bias ? bias[lane] : 0.f;
#pragma unroll
  for (int k = 0; k < 64; k++) acc += __shfl(rv, k, 64) * W[k * 64 + lane];
  out[r * 64 + lane] = acc;
}

// Fused setup: build Wt (bf16, n-major, 4 sections), c1, c2.
// Wt rows 0-63: W1_bot^T, 64-127: W2_bot^T, 128-191: W3_top^T, 192-255: W3_bot^T
__global__ __launch_bounds__(256) void k_prep(
    const float* __restrict__ ap_hid, const float* __restrict__ ue_hid,
    const float* __restrict__ W1, const float* __restrict__ b1,
    const float* __restrict__ W2, const float* __restrict__ b2,
    const float* __restrict__ W3, unsigned short* __restrict__ Wt,
    float* __restrict__ c1, float* __restrict__ c2) {
  int bx = blockIdx.x, tid = threadIdx.x;
  if (bx < 64) {
    int idx = bx * 256 + tid;  // 16384 total
    int r = idx >> 6, k = idx & 63;
    int sec = r >> 6, d = r & 63;
    float v;
    if (sec == 0)      v = W1[(64 + k) * 64 + d];
    else if (sec == 1) v = W2[(64 + k) * 64 + d];
    else if (sec == 2) v = W3[k * 64 + d];
    else               v = W3[(64 + k) * 64 + d];
    Wt[r * 64 + k] = f2bf(v);
  } else if (bx < 128) {
    int r = (bx - 64) * 4 + (tid >> 6);
    rowmlp_row(ap_hid, W1, b1, c1, r, tid & 63);
  } else {  // bx in [128, 384)
    int r = (bx - 128) * 4 + (tid >> 6);
    rowmlp_row(ue_hid, W2, b2, c2, r, tid & 63);
  }
}

// Pass 1 (atomic-free, R14 form): per-block PARTIAL sums, 8-a chunks.
//   ue_part[chunk][u][d] : register-accumulated over the block's 8 a's.
//   ap_part[panel][a][d] : cross-wave reduce via LDS accumulator.
// 512 blocks: chunk = bx>>4 (32 chunks of 8 a's), panel = bx&15 (16 u-panels).
__global__ __launch_bounds__(256) void k_pass1(
    const float* __restrict__ edge, const unsigned short* __restrict__ Wt,
    const float* __restrict__ c1, const float* __restrict__ c2,
    float* __restrict__ ap_part, float* __restrict__ ue_part) {
  __shared__ float ap_l[8 * 64];  // [slice c][d]
  int tid = threadIdx.x, lane = tid & 63, w = tid >> 6;
  int fr = lane & 15, fq = lane >> 4;
  int chunk = blockIdx.x >> 4;
  int panel = blockIdx.x & 15;
  int a0 = chunk * 8;
  int u0 = panel * 64;
  int urow = u0 + w * 16 + fr;
  const float* erow = edge + urow * 64 + fq * 8;  // + a*65536

  ap_l[tid] = 0.f;
  ap_l[tid + 256] = 0.f;
  __syncthreads();

  // loop-invariant B-fragments: n-tiles 0-3 = W1b, 4-7 = W2b (held in regs)
  short8 bw[8][2];
#pragma unroll
  for (int nt = 0; nt < 8; nt++)
#pragma unroll
    for (int ks = 0; ks < 2; ks++)
      bw[nt][ks] = *(const short8*)(Wt + (nt * 16 + fr) * 64 + ks * 32 + fq * 8);

  float c2v[4][4];
#pragma unroll
  for (int j = 0; j < 4; j++)
#pragma unroll
    for (int i = 0; i < 4; i++)
      c2v[j][i] = c2[(u0 + w * 16 + fq * 4 + i) * 64 + j * 16 + fr];

  float ureg[4][4];
#pragma unroll
  for (int j = 0; j < 4; j++)
#pragma unroll
    for (int i = 0; i < 4; i++) ureg[j][i] = 0.f;

  // prefetch slice a0
  const float* p0 = erow + a0 * 65536;
  float4 e0 = *(const float4*)(p0);
  float4 e1 = *(const float4*)(p0 + 4);
  float4 e2 = *(const float4*)(p0 + 32);
  float4 e3 = *(const float4*)(p0 + 36);
  float c1v[4];
#pragma unroll
  for (int j = 0; j < 4; j++) c1v[j] = c1[a0 * 64 + j * 16 + fr];

  for (int c = 0; c < 8; c++) {
    int a = a0 + c;
    float4 n0, n1, n2, n3;
    float nc1[4];
    if (c < 7) {
      const float* np = erow + (a + 1) * 65536;
      n0 = *(const float4*)(np);
      n1 = *(const float4*)(np + 4);
      n2 = *(const float4*)(np + 32);
      n3 = *(const float4*)(np + 36);
#pragma unroll
      for (int j = 0; j < 4; j++) nc1[j] = c1[(a + 1) * 64 + j * 16 + fr];
    }
    short8 af0, af1;
    cvt16(e0, e1, e2, e3, af0, af1);

    // P1 -> reduce over the wave's 16 u-rows -> LDS accumulator (cross-wave)
#pragma unroll
    for (int j = 0; j < 4; j++) {
      f32x4 acc = {0.f, 0.f, 0.f, 0.f};
      acc = mfma16(af0, bw[j][0], acc);
      acc = mfma16(af1, bw[j][1], acc);
      float cv = c1v[j];
      float rs = fmaxf(acc[0] + cv, 0.f) + fmaxf(acc[1] + cv, 0.f) +
                 fmaxf(acc[2] + cv, 0.f) + fmaxf(acc[3] + cv, 0.f);
      rs += __shfl_xor(rs, 16, 64);
      rs += __shfl_xor(rs, 32, 64);
      if (lane < 16) atomicAdd(&ap_l[c * 64 + j * 16 + lane], rs);  // LDS atomic
    }
    // P2 -> per-(u,d) register accumulation across the 8 a's
#pragma unroll
    for (int j = 0; j < 4; j++) {
      f32x4 acc = {0.f, 0.f, 0.f, 0.f};
      acc = mfma16(af0, bw[4 + j][0], acc);
      acc = mfma16(af1, bw[4 + j][1], acc);
#pragma unroll
      for (int i = 0; i < 4; i++)
        ureg[j][i] += fmaxf(acc[i] + c2v[j][i], 0.f);
    }
    if (c < 7) {
      e0 = n0; e1 = n1; e2 = n2; e3 = n3;
#pragma unroll
      for (int j = 0; j < 4; j++) c1v[j] = nc1[j];
    }
  }
  // ue partials: plain stores (this block is the unique writer for (chunk, u))
#pragma unroll
  for (int j = 0; j < 4; j++)
#pragma unroll
    for (int i = 0; i < 4; i++)
      ue_part[(chunk * 1024 + u0 + w * 16 + fq * 4 + i) * 64 + j * 16 + fr] =
          ureg[j][i];
  __syncthreads();
  // ap partials: two per thread (this block is the unique writer for (panel, a))
  ap_part[(panel * 256 + a0 + w) * 64 + lane] = ap_l[w * 64 + lane];
  ap_part[(panel * 256 + a0 + 4 + w) * 64 + lane] = ap_l[(4 + w) * 64 + lane];
}

// Mid (R14 form): reduce partials -> row sums -> fused row-MLP:
// s3 = ap_sum@W3b, s4 = ue_sum@W3b + b3.  320 blocks x 4 rows.
__global__ __launch_bounds__(256) void k_mid(
    const float* __restrict__ ap_part, const float* __restrict__ ue_part,
    const float* __restrict__ W3, const float* __restrict__ b3,
    float* __restrict__ s3, float* __restrict__ s4) {
  int bx = blockIdx.x, tid = threadIdx.x, lane = tid & 63;
  const float* W3b = W3 + 4096;
  if (bx < 64) {
    int r = bx * 4 + (tid >> 6);
    float v = 0.f;
#pragma unroll
    for (int p = 0; p < 16; p++) v += ap_part[(p * 256 + r) * 64 + lane];
    float acc = 0.f;
#pragma unroll
    for (int k = 0; k < 64; k++) acc += __shfl(v, k, 64) * W3b[k * 64 + lane];
    s3[r * 64 + lane] = acc;
  } else {  // bx in [64, 320)
    int r = (bx - 64) * 4 + (tid >> 6);
    float v = 0.f;
#pragma unroll
    for (int p = 0; p < 32; p++) v += ue_part[(p * 1024 + r) * 64 + lane];
    float acc = b3[lane];
#pragma unroll
    for (int k = 0; k < 64; k++) acc += __shfl(v, k, 64) * W3b[k * 64 + lane];
    s4[r * 64 + lane] = acc;
  }
}

// Pass 2: out = P3 - t@W3b + s3[a] + s4[u], t = relu(P1+c1)+relu(P2+c2).
// 256 blocks: ONE a x 16 u-panels, pipelined (was 4 panels / 1024 blocks).
// Edge A-frags AND c2/s4 scalars for panel p+1 prefetched into registers
// during panel p compute. Weights in padded LDS (one barrier, amortized over
// 16 panels); t round-trips through wave-private LDS rows (no barrier).
__global__ __launch_bounds__(256) void k_pass2(
    const float* __restrict__ edge, const unsigned short* __restrict__ Wt,
    const float* __restrict__ c1, const float* __restrict__ c2,
    const float* __restrict__ s3, const float* __restrict__ s4,
    float* __restrict__ out) {
  __shared__ unsigned short W_lds[256 * 72];  // 4 sections x 64 rows, pad->72
  __shared__ unsigned short t_lds[64 * 72];
  int tid = threadIdx.x, lane = tid & 63, w = tid >> 6;
  int fr = lane & 15, fq = lane >> 4;
  int a = blockIdx.x;

  // stage all weights into LDS (256 rows x 128B)
#pragma unroll
  for (int it = 0; it < 8; it++) {
    int r = it * 32 + (tid >> 3), seg = tid & 7;
    *(uint4*)&W_lds[r * 72 + seg * 8] = *(const uint4*)(Wt + r * 64 + seg * 8);
  }

  float c1v[4], s3v[4];
#pragma unroll
  for (int j = 0; j < 4; j++) {
    c1v[j] = c1[a * 64 + j * 16 + fr];
    s3v[j] = s3[a * 64 + j * 16 + fr];
  }

  // prefetch panel 0: edge tile + c2/s4 scalars (hide under staging barrier)
  const float* er0 = edge + (a * 1024 + w * 16 + fr) * 64 + fq * 8;
  float4 e0 = *(const float4*)(er0);
  float4 e1 = *(const float4*)(er0 + 4);
  float4 e2 = *(const float4*)(er0 + 32);
  float4 e3 = *(const float4*)(er0 + 36);
  float c2v[4][4], s4v[4][4];
#pragma unroll
  for (int j = 0; j < 4; j++)
#pragma unroll
    for (int i = 0; i < 4; i++) {
      int u = w * 16 + fq * 4 + i;
      c2v[j][i] = c2[u * 64 + j * 16 + fr];
      s4v[j][i] = s4[u * 64 + j * 16 + fr];
    }

  __syncthreads();

  for (int pnl = 0; pnl < 16; pnl++) {
    int upan = pnl * 64;
    float4 n0, n1, n2, n3;
    float c2n[4][4], s4n[4][4];
    if (pnl < 15) {
      const float* nr = edge + (a * 1024 + upan + 64 + w * 16 + fr) * 64 + fq * 8;
      n0 = *(const float4*)(nr);
      n1 = *(const float4*)(nr + 4);
      n2 = *(const float4*)(nr + 32);
      n3 = *(const float4*)(nr + 36);
#pragma unroll
      for (int j = 0; j < 4; j++)
#pragma unroll
        for (int i = 0; i < 4; i++) {
          int u = upan + 64 + w * 16 + fq * 4 + i;
          c2n[j][i] = c2[u * 64 + j * 16 + fr];
          s4n[j][i] = s4[u * 64 + j * 16 + fr];
        }
    }
    short8 af0, af1;
    cvt16(e0, e1, e2, e3, af0, af1);

    f32x4 accP3[4];
#pragma unroll
    for (int j = 0; j < 4; j++) {
      const unsigned short* wr = &W_lds[(j * 16 + fr) * 72 + fq * 8];
      short8 b10 = *(const short8*)(wr);
      short8 b11 = *(const short8*)(wr + 32);
      short8 b20 = *(const short8*)(wr + 64 * 72);
      short8 b21 = *(const short8*)(wr + 64 * 72 + 32);
      short8 b30 = *(const short8*)(wr + 128 * 72);
      short8 b31 = *(const short8*)(wr + 128 * 72 + 32);
      f32x4 a1 = {0.f, 0.f, 0.f, 0.f};
      a1 = mfma16(af0, b10, a1);
      a1 = mfma16(af1, b11, a1);
      f32x4 a2 = {0.f, 0.f, 0.f, 0.f};
      a2 = mfma16(af0, b20, a2);
      a2 = mfma16(af1, b21, a2);
      f32x4 p3 = {0.f, 0.f, 0.f, 0.f};
      p3 = mfma16(af0, b30, p3);
      p3 = mfma16(af1, b31, p3);
      accP3[j] = p3;
#pragma unroll
      for (int i = 0; i < 4; i++) {
        float tv = fmaxf(a1[i] + c1v[j], 0.f) + fmaxf(a2[i] + c2v[j][i], 0.f);
        t_lds[(w * 16 + fq * 4 + i) * 72 + j * 16 + fr] = f2bf(tv);  // wave-private
      }
    }
    // GEMM2: A = t (this wave's own rows; DS in-order per wave, no barrier)
    short8 tf0 = *(const short8*)&t_lds[(w * 16 + fr) * 72 + fq * 8];
    short8 tf1 = *(const short8*)&t_lds[(w * 16 + fr) * 72 + 32 + fq * 8];
#pragma unroll
    for (int j = 0; j < 4; j++) {
      const unsigned short* wr = &W_lds[(192 + j * 16 + fr) * 72 + fq * 8];
      short8 b0 = *(const short8*)(wr);
      short8 b1 = *(const short8*)(wr + 32);
      f32x4 acc = {0.f, 0.f, 0.f, 0.f};
      acc = mfma16(tf0, b0, acc);
      acc = mfma16(tf1, b1, acc);
#pragma unroll
      for (int i = 0; i < 4; i++) {
        int u = upan + w * 16 + fq * 4 + i;
        out[(a * 1024 + u) * 64 + j * 16 + fr] =
            accP3[j][i] - acc[i] + s3v[j] + s4v[j][i];
      }
    }
    if (pnl < 15) {
      e0 = n0; e1 = n1; e2 = n2; e3 = n3;
#pragma unroll
      for (int j = 0; j < 4; j++)
#pragma unroll
        for (int i = 0; i < 4; i++) {
          c2v[j][i] = c2n[j][i];
          s4v[j][i] = s4n[j][i];
        }
    }
  }
}

extern "C" void kernel_launch(void* const* d_in, const int* in_sizes, int n_in,
                              void* d_out, int out_size, void* d_ws, size_t ws_size,
                              hipStream_t stream) {
  const float* ap_hid = (const float*)d_in[0];
  const float* ue_hid = (const float*)d_in[1];
  const float* edge   = (const float*)d_in[2];
  const float* W1     = (const float*)d_in[3];
  const float* b1     = (const float*)d_in[4];
  const float* W2     = (const float*)d_in[5];
  const float* b2     = (const float*)d_in[6];
  const float* W3     = (const float*)d_in[7];
  const float* b3     = (const float*)d_in[8];
  float* out = (float*)d_out;

  char* ws = (char*)d_ws;
  unsigned short* Wt = (unsigned short*)ws;            //     32768 B
  float* c1      = (float*)(ws + 32768);               //     65536 B
  float* c2      = (float*)(ws + 98304);               //    262144 B
  float* s3      = (float*)(ws + 360448);              //     65536 B
  float* s4      = (float*)(ws + 425984);              //    262144 B
  float* ap_part = (float*)(ws + 688128);              //   4194304 B  [16][256][64]
  float* ue_part = (float*)(ws + 4882432);             //   8388608 B  [32][1024][64]

  k_prep<<<384, 256, 0, stream>>>(ap_hid, ue_hid, W1, b1, W2, b2, W3, Wt, c1, c2);
  k_pass1<<<512, 256, 0, stream>>>(edge, Wt, c1, c2, ap_part, ue_part);
  k_mid<<<320, 256, 0, stream>>>(ap_part, ue_part, W3, b3, s3, s4);
  k_pass2<<<256, 256, 0, stream>>>(edge, Wt, c1, c2, s3, s4, out);
}